// Round 4
// baseline (472.535 us; speedup 1.0000x reference)
//
#include <hip/hip_runtime.h>
#include <math.h>

#define DIM   1024
#define HALF  512
#define NROWS 65536
#define SBLK  4096   // k_scores blocks: 16 rows each (4 waves x 4 rows)
#define WBLK  2048   // k_wsum blocks: 32 rows each
#define WF1   64     // fold-1 blocks (32 partials each)

// ---- workspace layout (float offsets), atomic-free, no memset needed ----
#define OFF_SCAL   0                         // [0]=mean [1]=rstd
#define OFF_QACC   (OFF_SCAL + 8)            // [512]
#define OFF_PVEC   (OFF_QACC + HALF)         // [1024]
#define OFF_PSTAT  (OFF_PVEC + DIM)          // float2[SBLK]
#define OFF_S      (OFF_PSTAT + 2*SBLK)      // [65536]
#define OFF_INVN   (OFF_S + NROWS)           // [65536]
#define OFF_PESUM  (OFF_INVN + NROWS)        // [WBLK]
#define OFF_PW     (OFF_PESUM + WBLK)        // [WBLK*DIM] = 8 MB
#define OFF_P2     (OFF_PW + WBLK*DIM)       // [WF1*DIM]
#define OFF_WACC   (OFF_P2 + WF1*DIM)        // [1024]
#define OFF_OVACC  (OFF_WACC + DIM)          // [1024]
#define OFF_END    (OFF_OVACC + DIM)

// Fused: qn = l2norm(q_init); qacc[c4] = sum_r qn[r]*Wq[r][c4].
// Grid = HALF/4 = 128 blocks x 256 thr (one float4-column group per block).
__global__ void k_prep(const float* __restrict__ q_init,
                       const float* __restrict__ Wq,
                       float* __restrict__ qacc) {
    __shared__ float qs[DIM];
    __shared__ float4 red4[256];
    __shared__ float red[256];
    int t = threadIdx.x, c4 = blockIdx.x;
    float sq = 0.f;
    #pragma unroll
    for (int i = 0; i < 4; ++i) {
        float v = q_init[t + i * 256];
        qs[t + i * 256] = v;
        sq += v * v;
    }
    red[t] = sq;
    __syncthreads();
    for (int s = 128; s > 0; s >>= 1) {
        if (t < s) red[t] += red[t + s];
        __syncthreads();
    }
    float inv = 1.0f / fmaxf(sqrtf(red[0]), 1e-12f);
    const float4* W4 = (const float4*)Wq;
    float4 acc = make_float4(0.f, 0.f, 0.f, 0.f);
    for (int r = t; r < DIM; r += 256) {
        float c = qs[r] * inv;
        float4 m = W4[(size_t)r * (HALF / 4) + c4];
        acc.x += c * m.x; acc.y += c * m.y; acc.z += c * m.z; acc.w += c * m.w;
    }
    red4[t] = acc;
    __syncthreads();
    for (int s = 128; s > 0; s >>= 1) {
        if (t < s) {
            red4[t].x += red4[t + s].x; red4[t].y += red4[t + s].y;
            red4[t].z += red4[t + s].z; red4[t].w += red4[t + s].w;
        }
        __syncthreads();
    }
    if (t == 0) ((float4*)qacc)[c4] = red4[0];
}

// pvec[d] = sum_j Wk[d][j] * (qacc[j] + bq[j]); one wave per row d.
__global__ void k_pvec(const float* __restrict__ Wk,
                       const float* __restrict__ qacc,
                       const float* __restrict__ bq,
                       float* __restrict__ pvec) {
    __shared__ float q[HALF];
    int t = threadIdx.x; // 256
    for (int j = t; j < HALF; j += 256) q[j] = qacc[j] + bq[j];
    __syncthreads();
    int wave = t >> 6, lane = t & 63;
    int d = blockIdx.x * 4 + wave;
    const float* row = Wk + (size_t)d * HALF;
    float acc = 0.f;
    #pragma unroll
    for (int j0 = 0; j0 < HALF; j0 += 64) acc += row[j0 + lane] * q[j0 + lane];
    #pragma unroll
    for (int o = 32; o > 0; o >>= 1) acc += __shfl_down(acc, o);
    if (lane == 0) pvec[d] = acc;
}

// Pass 1: 4 rows/wave; all 16 float4 loads issued before use (max MLP).
// Per-block (sum s, sum s^2) stored — no atomics.
__global__ void k_scores(const float* __restrict__ K,
                         const float* __restrict__ pvec,
                         float* __restrict__ svals,
                         float* __restrict__ invn,
                         float2* __restrict__ pstat) {
    __shared__ float4 p4s[256];
    __shared__ float wsum[4], wssq[4];
    int t = threadIdx.x;
    p4s[t] = ((const float4*)pvec)[t];
    __syncthreads();
    int wave = t >> 6, lane = t & 63;
    int row0 = blockIdx.x * 16 + wave * 4;
    const float4* k4 = (const float4*)K + (size_t)row0 * 256 + lane;
    float4 v[16];
    #pragma unroll
    for (int r = 0; r < 4; ++r)
        #pragma unroll
        for (int i = 0; i < 4; ++i)
            v[r * 4 + i] = k4[r * 256 + i * 64];
    float d[4] = {0, 0, 0, 0}, q[4] = {0, 0, 0, 0};
    #pragma unroll
    for (int r = 0; r < 4; ++r) {
        #pragma unroll
        for (int i = 0; i < 4; ++i) {
            float4 a = v[r * 4 + i];
            float4 p = p4s[lane + i * 64];
            d[r] += a.x * p.x + a.y * p.y + a.z * p.z + a.w * p.w;
            q[r] += a.x * a.x + a.y * a.y + a.z * a.z + a.w * a.w;
        }
    }
    #pragma unroll
    for (int o = 32; o > 0; o >>= 1) {
        #pragma unroll
        for (int r = 0; r < 4; ++r) {
            d[r] += __shfl_down(d[r], o);
            q[r] += __shfl_down(q[r], o);
        }
    }
    if (lane == 0) {
        float i0 = 1.0f / fmaxf(sqrtf(q[0]), 1e-12f);
        float i1 = 1.0f / fmaxf(sqrtf(q[1]), 1e-12f);
        float i2 = 1.0f / fmaxf(sqrtf(q[2]), 1e-12f);
        float i3 = 1.0f / fmaxf(sqrtf(q[3]), 1e-12f);
        float s0 = d[0] * i0, s1 = d[1] * i1, s2 = d[2] * i2, s3 = d[3] * i3;
        *(float4*)(svals + row0) = make_float4(s0, s1, s2, s3);
        *(float4*)(invn + row0) = make_float4(i0, i1, i2, i3);
        wsum[wave] = s0 + s1 + s2 + s3;
        wssq[wave] = s0 * s0 + s1 * s1 + s2 * s2 + s3 * s3;
    }
    __syncthreads();
    if (t == 0)
        pstat[blockIdx.x] = make_float2(wsum[0] + wsum[1] + wsum[2] + wsum[3],
                                        wssq[0] + wssq[1] + wssq[2] + wssq[3]);
}

// Reduce SBLK partial stats -> scal[0]=mean, scal[1]=rstd. 1 block x 1024.
__global__ void k_redstats(const float2* __restrict__ pstat, float* __restrict__ scal) {
    __shared__ float rs[1024], rq[1024];
    int t = threadIdx.x;
    float s = 0.f, q = 0.f;
    for (int i = t; i < SBLK; i += 1024) {
        float2 p = pstat[i];
        s += p.x; q += p.y;
    }
    rs[t] = s; rq[t] = q;
    __syncthreads();
    for (int k = 512; k > 0; k >>= 1) {
        if (t < k) { rs[t] += rs[t + k]; rq[t] += rq[t + k]; }
        __syncthreads();
    }
    if (t == 0) {
        float mean = rs[0] / (float)NROWS;
        float var  = (rq[0] - (float)NROWS * mean * mean) / (float)(NROWS - 1);
        scal[0] = mean;
        scal[1] = 1.0f / (sqrtf(fmaxf(var, 0.0f)) + 1e-8f);
    }
}

// Pass 2 (coeff fused): block b (REVERSE order for L3 LRU) handles 32 rows:
//   e_r = exp(clip((s_r-mean)*rstd)), pw[b] = sum e_r*invn_r*K[r,:], pesum[b]=sum e_r.
// Loads batched 8-deep for MLP. No atomics.
__global__ void k_wsum(const float* __restrict__ K,
                       const float* __restrict__ svals,
                       const float* __restrict__ invn,
                       const float* __restrict__ scal,
                       float* __restrict__ pw,
                       float* __restrict__ pesum) {
    int t = threadIdx.x;
    int b = (int)gridDim.x - 1 - (int)blockIdx.x;
    int r0 = b * 32;
    float mean = scal[0], rstd = scal[1];
    const float4* M4 = (const float4*)K + (size_t)r0 * 256 + t;
    float4 acc = make_float4(0.f, 0.f, 0.f, 0.f);
    float esum = 0.f;
    #pragma unroll
    for (int rb = 0; rb < 32; rb += 8) {
        float4 m[8];
        #pragma unroll
        for (int r = 0; r < 8; ++r) m[r] = M4[(size_t)(rb + r) * 256];
        #pragma unroll
        for (int r = 0; r < 8; ++r) {
            int ri = r0 + rb + r;
            float z = (svals[ri] - mean) * rstd;
            z = fminf(fmaxf(z, -10.0f), 10.0f);
            float e = expf(z);
            esum += e;
            float c = e * invn[ri];
            acc.x += c * m[r].x; acc.y += c * m[r].y;
            acc.z += c * m[r].z; acc.w += c * m[r].w;
        }
    }
    ((float4*)pw)[(size_t)b * 256 + t] = acc;
    if (t == 0) pesum[b] = esum;
}

// Fold WBLK partials -> WF1 partials. WF1 blocks x 256 thr.
__global__ void k_wfold(const float* __restrict__ pw, float* __restrict__ p2) {
    int t = threadIdx.x, b = blockIdx.x;
    const float4* pw4 = (const float4*)pw;
    float4 acc = make_float4(0.f, 0.f, 0.f, 0.f);
    #pragma unroll
    for (int p = 0; p < WBLK / WF1; ++p) {
        float4 m = pw4[(size_t)(b * (WBLK / WF1) + p) * 256 + t];
        acc.x += m.x; acc.y += m.y; acc.z += m.z; acc.w += m.w;
    }
    ((float4*)p2)[b * 256 + t] = acc;
}

// Fold WF1 partials + reduce pesum[WBLK] -> wacc = w / sum(exp). 1 block x 1024.
__global__ void k_wreduce(const float* __restrict__ p2,
                          const float* __restrict__ pesum,
                          float* __restrict__ wacc) {
    __shared__ float red[1024];
    int t = threadIdx.x;
    float es = 0.f;
    for (int i = t; i < WBLK; i += 1024) es += pesum[i];
    red[t] = es;
    __syncthreads();
    for (int s = 512; s > 0; s >>= 1) {
        if (t < s) red[t] += red[t + s];
        __syncthreads();
    }
    float inv = 1.0f / red[0];
    float acc = 0.f;
    #pragma unroll
    for (int b = 0; b < WF1; ++b) acc += p2[b * DIM + t];
    wacc[t] = acc * inv;
}

// Column matvec: out[c4] = sum_r (coeff[r](+cbias[r])) * M[r][c4].
__global__ void k_mv(const float* __restrict__ M,
                     const float* __restrict__ coeff,
                     const float* __restrict__ cbias,
                     float* __restrict__ out) {
    __shared__ float4 red[256];
    int t = threadIdx.x, c4 = blockIdx.x;
    const float4* M4 = (const float4*)M;
    float4 acc = make_float4(0.f, 0.f, 0.f, 0.f);
    for (int r = t; r < DIM; r += 256) {
        float c = coeff[r];
        if (cbias) c += cbias[r];
        float4 m = M4[(size_t)r * (DIM / 4) + c4];
        acc.x += c * m.x; acc.y += c * m.y; acc.z += c * m.z; acc.w += c * m.w;
    }
    red[t] = acc;
    __syncthreads();
    for (int s = 128; s > 0; s >>= 1) {
        if (t < s) {
            red[t].x += red[t + s].x; red[t].y += red[t + s].y;
            red[t].z += red[t + s].z; red[t].w += red[t + s].w;
        }
        __syncthreads();
    }
    if (t == 0) ((float4*)out)[c4] = red[0];
}

// Same as k_mv but with the final gate epilogue:
// out[c4] = g*q_init[c4] + (1-g)*(acc[c4] + bm[c4]), g = sigmoid(gamma).
__global__ void k_mv_final(const float* __restrict__ M,
                           const float* __restrict__ coeff,
                           const float* __restrict__ cbias,
                           const float* __restrict__ q_init,
                           const float* __restrict__ bm,
                           const float* __restrict__ gamma,
                           float* __restrict__ out) {
    __shared__ float4 red[256];
    int t = threadIdx.x, c4 = blockIdx.x;
    const float4* M4 = (const float4*)M;
    float4 acc = make_float4(0.f, 0.f, 0.f, 0.f);
    for (int r = t; r < DIM; r += 256) {
        float c = coeff[r] + cbias[r];
        float4 m = M4[(size_t)r * (DIM / 4) + c4];
        acc.x += c * m.x; acc.y += c * m.y; acc.z += c * m.z; acc.w += c * m.w;
    }
    red[t] = acc;
    __syncthreads();
    for (int s = 128; s > 0; s >>= 1) {
        if (t < s) {
            red[t].x += red[t + s].x; red[t].y += red[t + s].y;
            red[t].z += red[t + s].z; red[t].w += red[t + s].w;
        }
        __syncthreads();
    }
    if (t == 0) {
        float g = 1.0f / (1.0f + expf(-gamma[0]));
        float4 qv = ((const float4*)q_init)[c4];
        float4 bmv = ((const float4*)bm)[c4];
        float4 o;
        o.x = g * qv.x + (1.0f - g) * (red[0].x + bmv.x);
        o.y = g * qv.y + (1.0f - g) * (red[0].y + bmv.y);
        o.z = g * qv.z + (1.0f - g) * (red[0].z + bmv.z);
        o.w = g * qv.w + (1.0f - g) * (red[0].w + bmv.w);
        ((float4*)out)[c4] = o;
    }
}

extern "C" void kernel_launch(void* const* d_in, const int* in_sizes, int n_in,
                              void* d_out, int out_size, void* d_ws, size_t ws_size,
                              hipStream_t stream) {
    const float* q_init = (const float*)d_in[0];
    const float* k_init = (const float*)d_in[1];
    const float* Wq     = (const float*)d_in[2];
    const float* bq     = (const float*)d_in[3];
    const float* Wk     = (const float*)d_in[4];
    // d_in[5] = bk: constant shift of all scores -> cancels in standardization
    const float* Wv     = (const float*)d_in[6];
    const float* bv     = (const float*)d_in[7];
    const float* Wm     = (const float*)d_in[8];
    const float* bm     = (const float*)d_in[9];
    const float* gamma  = (const float*)d_in[10];
    float* out = (float*)d_out;
    float* ws  = (float*)d_ws;

    float*  scal   = ws + OFF_SCAL;
    float*  qacc   = ws + OFF_QACC;
    float*  pvec   = ws + OFF_PVEC;
    float2* pstat  = (float2*)(ws + OFF_PSTAT);
    float*  svals  = ws + OFF_S;
    float*  invn   = ws + OFF_INVN;
    float*  pesum  = ws + OFF_PESUM;
    float*  pw     = ws + OFF_PW;
    float*  p2     = ws + OFF_P2;
    float*  wacc   = ws + OFF_WACC;
    float*  ovacc  = ws + OFF_OVACC;

    // q = l2norm(q_init) @ Wq (bq folded in at k_pvec)
    k_prep<<<HALF / 4, 256, 0, stream>>>(q_init, Wq, qacc);
    // pvec = Wk @ (q + bq)
    k_pvec<<<DIM / 4, 256, 0, stream>>>(Wk, qacc, bq, pvec);
    // pass 1: scores + inv norms + per-block stats partials
    k_scores<<<SBLK, 256, 0, stream>>>(k_init, pvec, svals, invn, pstat);
    k_redstats<<<1, 1024, 0, stream>>>(pstat, scal);
    // pass 2 (coeff fused, reverse order): private partials
    k_wsum<<<WBLK, 256, 0, stream>>>(k_init, svals, invn, scal, pw, pesum);
    k_wfold<<<WF1, 256, 0, stream>>>(pw, p2);
    k_wreduce<<<1, 1024, 0, stream>>>(p2, pesum, wacc);
    // ov = w @ Wv ; out = gate(q_init, (ov + bv) @ Wm + bm)
    k_mv<<<DIM / 4, 256, 0, stream>>>(Wv, wacc, nullptr, ovacc);
    k_mv_final<<<DIM / 4, 256, 0, stream>>>(Wm, ovacc, bv, q_init, bm, gamma, out);
}